// Round 12
// baseline (182.793 us; speedup 1.0000x reference)
//
#include <hip/hip_runtime.h>

// ---------------------------------------------------------------------------
// MNIST Langevin Encoder — round 12: LDS-FREE gemm1 + copy riding every
// dispatch (heterogeneous blocks). r7/r8's overlap failed because copy blocks
// inherited the gemm's static LDS allocation (occupancy cap -> 2.7 TB/s);
// gemm1 is now LDS-free (A and B both direct global->reg from fragment-major
// packed buffers), so copy blocks co-reside at full occupancy.
//   dispatch 0: zero_win (full array; langevin-phase copy reads all rows)
//   dispatch 1: P  = pack(Xp, W1p, Wout) + winner + copy chunk
//   dispatch 2: G1 = gemm1 (LDS-free) + copy chunk
//   dispatch 3: G2 = gemm2 + copy chunk
//   dispatch 4: L  = langevin(+scatter) + winner-skip copy chunk
// ---------------------------------------------------------------------------

#define ZD 64
#define NSTEPS 25
#define EPSI 0.01f
#define K1 784
#define HSTR 512   // padded hidden stride (bf16 h)

typedef __attribute__((ext_vector_type(8))) short short8;
typedef __attribute__((ext_vector_type(4))) float f32x4;
typedef __attribute__((ext_vector_type(4))) int i32x4;

__device__ __forceinline__ unsigned short f2bf(float f) {
  union { float f; unsigned u; } v; v.f = f;
  return (unsigned short)((v.u + 0x7FFFu + ((v.u >> 16) & 1u)) >> 16);
}

__device__ __forceinline__ void gload_lds16(const void* g, void* l) {
  __builtin_amdgcn_global_load_lds(
      (const __attribute__((address_space(1))) void*)g,
      (__attribute__((address_space(3))) void*)l, 16, 0, 0);
}

// plain copy role: 4 float4/thread (strided by blockDim), guarded.
__device__ __forceinline__ void copy_role(const f32x4* __restrict__ src,
                                          f32x4* __restrict__ dst,
                                          long e0, int bdim, long n4) {
#pragma unroll
  for (int g = 0; g < 4; g++) {
    const long e = e0 + (long)g * bdim;
    if (e < n4) dst[e] = src[e];
  }
}

// ---------------- dispatch 0: zero winner array ----------------------------
__global__ __launch_bounds__(256) void zero_win_kernel(i32x4* __restrict__ win4, int n4i) {
  const int t = blockIdx.x * 256 + threadIdx.x;
  if (t < n4i) win4[t] = (i32x4){0, 0, 0, 0};
}

// ---------------- dispatch 1: pack + winner + copy --------------------------
// Xp slot t: l=t&63; q=(t>>6)>>2; rg=(t>>6)&3; kc=q%25; m=q/25;
//   value = x[m*64 + rg*16 + (l&15)][kc*32 + (l>>4)*8 .. +8] as bf16 (pad 0)
// W1p slot t: g=t/1600; kc32=(t%1600)>>6; l=t&63;
//   value = W1[g*16 + (l&15)][kc32*32 + (l>>4)*8 .. +8]
// Wout: [128][512] row-major bf16.
#define XPSLOTS 1638400              // 256*100*64
#define WSLOTS  59392                // 51200 + 8192
#define PACKBLK 6632                 // (XPSLOTS + WSLOTS) / 256
#define PCOPY   3000
#define PWIN    64
__global__ __launch_bounds__(256) void pack_copy_kernel(
    const float* __restrict__ X, const float* __restrict__ W1,
    const float* __restrict__ W21, const float* __restrict__ W22,
    short* __restrict__ Xp, short* __restrict__ W1p, short* __restrict__ Wout,
    const int* __restrict__ idx, int* __restrict__ winner, int B,
    const f32x4* __restrict__ cache4, f32x4* __restrict__ out4, long n4) {
  const int tid = threadIdx.x;
  const int bx = blockIdx.x;
  if (bx < PACKBLK) {
    const int t = bx * 256 + tid;
    if (t < XPSLOTS) {
      const int l = t & 63;
      const int c = t >> 6;
      const int rg = c & 3;
      const int q = c >> 2;
      const int kc = q % 25;
      const int m = q / 25;
      const int row = m * 64 + rg * 16 + (l & 15);
      const int k = kc * 32 + (l >> 4) * 8;
      short8 v = {0, 0, 0, 0, 0, 0, 0, 0};
      if (k + 8 <= K1) {
        const float* s = X + (long)row * K1 + k;
        const float4 f0 = *(const float4*)(s);
        const float4 f1 = *(const float4*)(s + 4);
        v[0] = (short)f2bf(f0.x); v[1] = (short)f2bf(f0.y);
        v[2] = (short)f2bf(f0.z); v[3] = (short)f2bf(f0.w);
        v[4] = (short)f2bf(f1.x); v[5] = (short)f2bf(f1.y);
        v[6] = (short)f2bf(f1.z); v[7] = (short)f2bf(f1.w);
      }
      *(short8*)(Xp + (long)t * 8) = v;
    } else {
      const int u = t - XPSLOTS;
      if (u < 51200) {               // W1p
        const int g = u / 1600;
        const int rem = u - g * 1600;
        const int kc32 = rem >> 6;
        const int l = rem & 63;
        const int col = g * 16 + (l & 15);
        const int k = kc32 * 32 + (l >> 4) * 8;
        short8 v = {0, 0, 0, 0, 0, 0, 0, 0};
        if (col < 400 && k + 8 <= K1) {
          const float* s = W1 + (long)col * K1 + k;
#pragma unroll
          for (int e = 0; e < 8; e++) v[e] = (short)f2bf(s[e]);
        }
        *(short8*)(W1p + (long)u * 8) = v;
      } else {                       // Wout
        const int q2 = u - 51200;    // 0..8191
        const int n = q2 / 64, k0 = (q2 % 64) * 8;
        short8 v = {0, 0, 0, 0, 0, 0, 0, 0};
        if (k0 < 400) {
          const float* s = (n < 64) ? (W21 + (long)n * 400 + k0)
                                    : (W22 + (long)(n - 64) * 400 + k0);
#pragma unroll
          for (int e = 0; e < 8; e++) v[e] = (short)f2bf(s[e]);
        }
        *(short8*)(Wout + (long)q2 * 8) = v;
      }
    }
  } else if (bx < PACKBLK + PCOPY) {
    const long e0 = (long)(bx - PACKBLK) * 1024 + tid;
    copy_role(cache4, out4, e0, 256, n4);
  } else {
    const int j = (bx - PACKBLK - PCOPY) * 256 + tid;
    if (j < B) atomicMax(&winner[idx[j]], j + 1);
  }
}

// ---------------- dispatch 2: gemm1 (LDS-free) + copy ----------------------
// gemm blocks [0,256): 64 rows x 512 cols, 8 waves, A/B direct global->reg.
#define NG1 256
#define C1  1500
__global__ __launch_bounds__(512) void gemm1_copy_kernel(
    const short* __restrict__ Xp, const short* __restrict__ W1p,
    const float* __restrict__ b1, unsigned short* __restrict__ H,
    const f32x4* __restrict__ cache4, f32x4* __restrict__ out4,
    long cbase, long n4) {
  const int tid = threadIdx.x;
  if ((int)blockIdx.x >= NG1) {
    const long e0 = cbase + (long)(blockIdx.x - NG1) * 2048 + tid;
    copy_role(cache4, out4, e0, 512, n4);
    return;
  }
  const int w = tid >> 6;
  const int lane = tid & 63;
  const int m = blockIdx.x;
  const int m0 = m * 64;

  const f32x4 vzero = {0.f, 0.f, 0.f, 0.f};
  f32x4 acc[4][4];
#pragma unroll
  for (int i = 0; i < 4; i++)
#pragma unroll
    for (int j = 0; j < 4; j++) acc[i][j] = vzero;

  const short8* Ap = (const short8*)Xp;
  const short8* Bp = (const short8*)W1p;
  const long abase = (long)m * 100 * 64;
  for (int kc = 0; kc < 25; kc++) {
    short8 a[4], b[4];
#pragma unroll
    for (int rg = 0; rg < 4; rg++) a[rg] = Ap[abase + (kc * 4 + rg) * 64 + lane];
#pragma unroll
    for (int j = 0; j < 4; j++) b[j] = Bp[((w * 4 + j) * 25 + kc) * 64 + lane];
#pragma unroll
    for (int rg = 0; rg < 4; rg++)
#pragma unroll
      for (int j = 0; j < 4; j++)
        acc[rg][j] = __builtin_amdgcn_mfma_f32_16x16x32_bf16(a[rg], b[j], acc[rg][j], 0, 0, 0);
  }

  const int colg = lane & 15;
  const int rowg = (lane >> 4) * 4;
#pragma unroll
  for (int j = 0; j < 4; j++) {
    const int col = w * 64 + j * 16 + colg;
    const float bias = (col < 400) ? b1[col] : 0.f;
#pragma unroll
    for (int rg = 0; rg < 4; rg++) {
      const int rbase = m0 + rg * 16 + rowg;
#pragma unroll
      for (int r = 0; r < 4; r++) {
        H[(long)(rbase + r) * HSTR + col] = f2bf(fmaxf(acc[rg][j][r] + bias, 0.f));
      }
    }
  }
}

// ---------------- dispatch 3: gemm2 (BM=32) + copy -------------------------
#define NG2 512
#define C2  3000
__global__ __launch_bounds__(256) void gemm2_copy_kernel(
    const unsigned short* __restrict__ H, const short* __restrict__ Wout,
    const float* __restrict__ b21, const float* __restrict__ b22,
    float* __restrict__ zloc, float* __restrict__ uarr,
    const f32x4* __restrict__ cache4, f32x4* __restrict__ out4,
    long cbase, long n4) {
  __shared__ short As[2 * 64 * 8];   // 2 KB
  __shared__ short Bs[8 * 64 * 8];   // 8 KB
  const int tid = threadIdx.x;
  if ((int)blockIdx.x >= NG2) {
    const long e0 = cbase + (long)(blockIdx.x - NG2) * 1024 + tid;
    copy_role(cache4, out4, e0, 256, n4);
    return;
  }
  const int w = tid >> 6;
  const int lane = tid & 63;
  const int m0 = blockIdx.x * 32;

  const f32x4 vzero = {0.f, 0.f, 0.f, 0.f};
  f32x4 acc[2][2];
#pragma unroll
  for (int i = 0; i < 2; i++)
#pragma unroll
    for (int j = 0; j < 2; j++) acc[i][j] = vzero;

  for (int k0 = 0; k0 < HSTR; k0 += 32) {
    if (k0) __syncthreads();
    if (w < 2) {
      const unsigned short* src = H + (long)(m0 + w * 16 + (lane & 15)) * HSTR +
                                  k0 + (lane >> 4) * 8;
      gload_lds16(src, As + w * 512);
    }
#pragma unroll
    for (int t = 0; t < 2; t++) {
      const int gn = w * 2 + t;
      const short* src = Wout + (long)(gn * 16 + (lane & 15)) * HSTR +
                         k0 + (lane >> 4) * 8;
      gload_lds16(src, Bs + gn * 512);
    }
    __syncthreads();
    const short8* Ap = (const short8*)As;
    const short8* Bp = (const short8*)Bs;
    const short8 a0 = Ap[0 * 64 + lane];
    const short8 a1 = Ap[1 * 64 + lane];
#pragma unroll
    for (int j = 0; j < 2; j++) {
      const short8 b = Bp[(w * 2 + j) * 64 + lane];
      acc[0][j] = __builtin_amdgcn_mfma_f32_16x16x32_bf16(a0, b, acc[0][j], 0, 0, 0);
      acc[1][j] = __builtin_amdgcn_mfma_f32_16x16x32_bf16(a1, b, acc[1][j], 0, 0, 0);
    }
  }
  const int colg = lane & 15;
  const int rowg = (lane >> 4) * 4;
  float* outp = (w < 2) ? zloc : uarr;
  const float* bp = (w < 2) ? b21 : b22;
#pragma unroll
  for (int j = 0; j < 2; j++) {
    const int col = (w & 1) * 32 + j * 16 + colg;
    const float bias = bp[col];
#pragma unroll
    for (int i = 0; i < 2; i++) {
      const int rbase = m0 + i * 16 + rowg;
#pragma unroll
      for (int r = 0; r < 4; r++) {
        outp[(long)(rbase + r) * ZD + col] = acc[i][j][r] + bias;
      }
    }
  }
}

// ---------------- dispatch 4: langevin(+scatter) + winner-skip copy --------
#define NL 4096
__global__ __launch_bounds__(256) void langevin_copy_kernel(
    const float* __restrict__ zloc, const float* __restrict__ uarr,
    const float* __restrict__ cache, const int* __restrict__ idx,
    const float* __restrict__ noise, const int* __restrict__ winner,
    float* __restrict__ out_logq, float* __restrict__ out_z,
    float* __restrict__ out_cache, int B, long cbase, long n4) {
  const int tid = threadIdx.x;
  if ((int)blockIdx.x >= NL) {
    // winner-skip copy: langevin blocks own the winner rows (disjoint).
    const long e0 = cbase + (long)(blockIdx.x - NL) * 1024 + tid;
    const f32x4* cache4 = (const f32x4*)cache;
    f32x4* out4 = (f32x4*)out_cache;
#pragma unroll
    for (int g = 0; g < 4; g++) {
      const long e = e0 + (long)g * 256;
      if (e < n4 && winner[e >> 4] == 0) out4[e] = cache4[e];
    }
    return;
  }
  const int row = blockIdx.x * 4 + (tid >> 6);
  const int lane = tid & 63;
  const int i = idx[row];
  const float zl = zloc[(long)row * ZD + lane];
  const float uu = uarr[(long)row * ZD + lane];
  const float a = EPSI * expf(-2.f * uu);  // EPS * inv_var
  float z = cache[(long)i * ZD + lane];
  const float coef = sqrtf(2.f * EPSI);
  const float* np = noise + (long)row * ZD + lane;
  const long stride = (long)B * ZD;
#pragma unroll
  for (int s = 0; s < NSTEPS; s++) {
    z = z + a * (zl - z) + coef * np[(long)s * stride];
  }
  out_z[(long)row * ZD + lane] = z;
  if (winner[i] == row + 1) {
    out_cache[(long)i * ZD + lane] = z;
  }
  const float d = (z - zl) * expf(-uu);
  float t = -0.5f * d * d - uu - 0.91893853320467274178f;
#pragma unroll
  for (int off = 1; off < 64; off <<= 1) t += __shfl_xor(t, off);
  if (lane == 0) out_logq[row] = t;
}

extern "C" void kernel_launch(void* const* d_in, const int* in_sizes, int n_in,
                              void* d_out, int out_size, void* d_ws, size_t ws_size,
                              hipStream_t stream) {
  const float* x     = (const float*)d_in[0];
  const int*   idx   = (const int*)d_in[1];
  const float* W1    = (const float*)d_in[3];
  const float* b1    = (const float*)d_in[4];
  const float* W21   = (const float*)d_in[5];
  const float* b21   = (const float*)d_in[6];
  const float* W22   = (const float*)d_in[7];
  const float* b22   = (const float*)d_in[8];
  const float* cache = (const float*)d_in[9];
  const float* noise = (const float*)d_in[10];

  const int B  = in_sizes[1];            // 16384
  const int DS = in_sizes[9] / ZD;       // 1000000

  float* out_logq  = (float*)d_out;
  float* out_z     = out_logq + B;
  float* out_cache = out_z + (long)B * ZD;

  // workspace layout (~50 MB: h 16MB + Xp 26MB + W 1MB + zloc/u 8MB + win 4MB)
  unsigned short* h = (unsigned short*)d_ws;              // B*512 bf16
  short* xp   = (short*)(h + (long)B * HSTR);             // 1638400*8 bf16 (26MB)
  short* w1p  = xp + (long)XPSLOTS * 8;                   // 51200*8 bf16
  short* wout = w1p + 51200 * 8;                          // 8192*8 bf16
  float* zloc = (float*)(wout + 8192 * 8);                // B*64 f32
  float* u    = zloc + (long)B * ZD;                      // B*64 f32
  int*   win  = (int*)(u + (long)B * ZD);                 // DS ints

  const long n4 = (long)DS * (ZD / 4);                    // 16,000,000 float4

  const int n4i = (DS + 3) / 4;
  zero_win_kernel<<<(n4i + 255) / 256, 256, 0, stream>>>((i32x4*)win, n4i);

  pack_copy_kernel<<<PACKBLK + PCOPY + PWIN, 256, 0, stream>>>(
      x, W1, W21, W22, xp, w1p, wout, idx, win, B,
      (const f32x4*)cache, (f32x4*)out_cache, n4);

  const long cbase1 = (long)PCOPY * 1024;                 // 3,072,000
  gemm1_copy_kernel<<<NG1 + C1, 512, 0, stream>>>(
      xp, w1p, b1, h, (const f32x4*)cache, (f32x4*)out_cache, cbase1, n4);

  const long cbase2 = cbase1 + (long)C1 * 2048;           // 6,144,000
  gemm2_copy_kernel<<<NG2 + C2, 256, 0, stream>>>(
      h, wout, b21, b22, zloc, u, (const f32x4*)cache, (f32x4*)out_cache,
      cbase2, n4);

  const long cbase3 = cbase2 + (long)C2 * 1024;           // 9,216,000
  const long rem = n4 - cbase3;                           // 6,784,000
  const int c3 = (int)((rem + 1023) / 1024);              // 6625
  langevin_copy_kernel<<<NL + c3, 256, 0, stream>>>(
      zloc, u, cache, idx, noise, win, out_logq, out_z, out_cache,
      B, cbase3, n4);
}

// Round 13
// 175.761 us; speedup vs baseline: 1.0400x; 1.0400x over previous
//
#include <hip/hip_runtime.h>

// ---------------------------------------------------------------------------
// MNIST Langevin Encoder — round 13: MEGA-FUSION. The encoder->langevin chain
// is block-local (64 rows/block): gemm1 (barrier-free, r11-verified) -> h in
// LDS (reuses stage-A space) -> gemm2 from LDS-h x frag-packed Wout -> zloc/u
// in LDS -> langevin + logq + scatter. Deletes h (32MB) and zloc/u (16MB)
// round-trips and 2 dispatches.
// Pipeline: zero_win -> prep -> winner -> copy (r11 kernel) -> mega
// ---------------------------------------------------------------------------

#define ZD 64
#define NSTEPS 25
#define EPSI 0.01f
#define K1 784
#define HSTR 512

typedef __attribute__((ext_vector_type(8))) short short8;
typedef __attribute__((ext_vector_type(4))) float f32x4;
typedef __attribute__((ext_vector_type(4))) int i32x4;

__device__ __forceinline__ unsigned short f2bf(float f) {
  union { float f; unsigned u; } v; v.f = f;
  return (unsigned short)((v.u + 0x7FFFu + ((v.u >> 16) & 1u)) >> 16);
}

// ---------------- prep: W1p (frag-major) + Woutp (frag-major) --------------
// W1p slot = (g*25 + kc32)*64 + l  : W1[g*16+(l&15)][kc32*32+(l>>4)*8..+8]
// Woutp slot = (g*16 + kc32)*64 + l: Wrow[g*16+(l&15)][kc32*32+(l>>4)*8..+8]
//   where Wrow n = W21 row n (n<64) else W22 row n-64; K=400 padded to 512.
#define NW1SLOTS 51200
#define NWOSLOTS 8192
__global__ __launch_bounds__(256) void prep_kernel(
    const float* __restrict__ W1, const float* __restrict__ W21,
    const float* __restrict__ W22, short* __restrict__ W1p,
    short* __restrict__ Woutp) {
  const int t = blockIdx.x * 256 + threadIdx.x;
  if (t < NW1SLOTS) {
    const int g = t / 1600;
    const int rem = t - g * 1600;
    const int kc32 = rem >> 6;
    const int l = rem & 63;
    const int col = g * 16 + (l & 15);
    const int k = kc32 * 32 + (l >> 4) * 8;
    short8 v = {0, 0, 0, 0, 0, 0, 0, 0};
    if (col < 400 && k + 8 <= K1) {
      const float* s = W1 + (long)col * K1 + k;
#pragma unroll
      for (int e = 0; e < 8; e++) v[e] = (short)f2bf(s[e]);
    }
    *(short8*)(W1p + (long)t * 8) = v;
  } else {
    const int u = t - NW1SLOTS;
    if (u < NWOSLOTS) {
      const int g = u >> 10;            // u / 1024
      const int rem = u & 1023;
      const int kc32 = rem >> 6;
      const int l = u & 63;
      const int row = g * 16 + (l & 15);    // 0..127
      const int k = kc32 * 32 + (l >> 4) * 8;
      short8 v = {0, 0, 0, 0, 0, 0, 0, 0};
      if (k + 8 <= 400) {
        const float* s = (row < 64) ? (W21 + (long)row * 400 + k)
                                    : (W22 + (long)(row - 64) * 400 + k);
#pragma unroll
        for (int e = 0; e < 8; e++) v[e] = (short)f2bf(s[e]);
      }
      *(short8*)(Woutp + (long)u * 8) = v;
    }
  }
}

// ---------------- zero winner array ----------------------------------------
__global__ __launch_bounds__(256) void zero_win_kernel(i32x4* __restrict__ win4, int n4i) {
  const int t = blockIdx.x * 256 + threadIdx.x;
  if (t < n4i) win4[t] = (i32x4){0, 0, 0, 0};
}

// ---------------- winner: last duplicate index wins ------------------------
__global__ __launch_bounds__(256) void winner_kernel(
    const int* __restrict__ idx, int* __restrict__ winner, int B) {
  const int j = blockIdx.x * 256 + threadIdx.x;
  if (j < B) atomicMax(&winner[idx[j]], j + 1);
}

// ---------------- stream copy (r11, proven): 4 float4/thread ---------------
__global__ __launch_bounds__(256) void copy_kernel(
    const f32x4* __restrict__ src, f32x4* __restrict__ dst) {
  const long base = (long)blockIdx.x * 1024 + threadIdx.x;
  f32x4 v0 = src[base];
  f32x4 v1 = src[base + 256];
  f32x4 v2 = src[base + 512];
  f32x4 v3 = src[base + 768];
  dst[base] = v0;
  dst[base + 256] = v1;
  dst[base + 512] = v2;
  dst[base + 768] = v3;
}

// ---------------- MEGA: gemm1 -> gemm2 -> langevin, block = 64 rows --------
// LDS: [0,100KB) stage-A (6400 short8); after gemm1 reused as:
//   [0,64KB)  h frag-major (4096 short8)
//   [64KB,80KB) zloc f32 [64][64]
//   [80KB,96KB) u    f32 [64][64]
__global__ __launch_bounds__(512, 2) void mega_kernel(
    const float* __restrict__ X, const short* __restrict__ W1p,
    const short* __restrict__ Woutp, const float* __restrict__ b1,
    const float* __restrict__ b21, const float* __restrict__ b22,
    const float* __restrict__ cache, const int* __restrict__ idx,
    const float* __restrict__ noise, const int* __restrict__ winner,
    float* __restrict__ out_logq, float* __restrict__ out_z,
    float* __restrict__ out_cache, int B) {
  __shared__ char smem[102400];
  const int tid = threadIdx.x;
  const int w = tid >> 6;
  const int lane = tid & 63;
  const int m0 = blockIdx.x * 64;

  // ---- phase 1: stage x-tile (64x800 bf16, frag-major) ----
  {
    short* As = (short*)smem;
    for (int slot = tid; slot < 6400; slot += 512) {
      const int lp = slot & 63;
      const int chunk = slot >> 6;       // kc32*4 + rg
      const int rg = chunk & 3;
      const int kc32 = chunk >> 2;
      const int row = rg * 16 + (lp & 15);
      const int k = kc32 * 32 + (lp >> 4) * 8;
      short8 av = {0, 0, 0, 0, 0, 0, 0, 0};
      if (k + 8 <= K1) {
        const float4 f0 = *(const float4*)(X + (long)(m0 + row) * K1 + k);
        const float4 f1 = *(const float4*)(X + (long)(m0 + row) * K1 + k + 4);
        av[0] = (short)f2bf(f0.x); av[1] = (short)f2bf(f0.y);
        av[2] = (short)f2bf(f0.z); av[3] = (short)f2bf(f0.w);
        av[4] = (short)f2bf(f1.x); av[5] = (short)f2bf(f1.y);
        av[6] = (short)f2bf(f1.z); av[7] = (short)f2bf(f1.w);
      }
      *(short8*)(As + (long)slot * 8) = av;
    }
  }
  __syncthreads();

  // ---- phase 2: gemm1 K-loop (barrier-free, r11-verified) ----
  const f32x4 vzero = {0.f, 0.f, 0.f, 0.f};
  f32x4 acc[4][4];
#pragma unroll
  for (int i = 0; i < 4; i++)
#pragma unroll
    for (int j = 0; j < 4; j++) acc[i][j] = vzero;
  {
    const short8* Ap = (const short8*)smem;
    const short8* Bp = (const short8*)W1p;
    for (int kc = 0; kc < 25; kc++) {
      short8 a[4], b[4];
#pragma unroll
      for (int rg = 0; rg < 4; rg++) a[rg] = Ap[(kc * 4 + rg) * 64 + lane];
#pragma unroll
      for (int j = 0; j < 4; j++) b[j] = Bp[((w * 4 + j) * 25 + kc) * 64 + lane];
#pragma unroll
      for (int rg = 0; rg < 4; rg++)
#pragma unroll
        for (int j = 0; j < 4; j++)
          acc[rg][j] = __builtin_amdgcn_mfma_f32_16x16x32_bf16(a[rg], b[j], acc[rg][j], 0, 0, 0);
    }
  }
  __syncthreads();   // all waves done reading stage-A

  // ---- phase 3: h (bias+relu, bf16) -> LDS frag-major ----
  {
    unsigned short* hl = (unsigned short*)smem;
#pragma unroll
    for (int j = 0; j < 4; j++) {
      const int col = w * 64 + j * 16 + (lane & 15);
      const float bias = (col < 400) ? b1[col] : 0.f;
#pragma unroll
      for (int rg = 0; rg < 4; rg++) {
#pragma unroll
        for (int r = 0; r < 4; r++) {
          const int row = rg * 16 + (lane >> 4) * 4 + r;
          const float v = fmaxf(acc[rg][j][r] + bias, 0.f);
          const int sidx = (((col >> 5) * 4 + (row >> 4)) * 64 + (row & 15) +
                            (((col >> 3) & 3) << 4)) * 8 + (col & 7);
          hl[sidx] = f2bf(v);
        }
      }
    }
  }
  __syncthreads();

  // ---- phase 4: gemm2 (64x128 = h @ Wout^T), K=512 from LDS-h ----
  // wave w: row-group rg2 = w>>1 (16 rows), cols c0=(w&1)*64 .. +63.
  f32x4 acc2[4];
#pragma unroll
  for (int j = 0; j < 4; j++) acc2[j] = vzero;
  {
    const short8* Hp = (const short8*)smem;
    const short8* Bp = (const short8*)Woutp;
    const int rg2 = w >> 1;
    const int gbase = (w & 1) * 4;
    for (int kc32 = 0; kc32 < 16; kc32++) {
      const short8 a = Hp[(kc32 * 4 + rg2) * 64 + lane];
#pragma unroll
      for (int j = 0; j < 4; j++) {
        const short8 b = Bp[((gbase + j) * 16 + kc32) * 64 + lane];
        acc2[j] = __builtin_amdgcn_mfma_f32_16x16x32_bf16(a, b, acc2[j], 0, 0, 0);
      }
    }
  }

  // ---- phase 5: zloc/u -> LDS (disjoint from h region; no barrier needed) --
  {
    float* zl = (float*)(smem + 65536);
    float* ul = (float*)(smem + 81920);
    const int rg2 = w >> 1;
    const bool is_u = (w & 1);
    const float* bp = is_u ? b22 : b21;
    float* outp = is_u ? ul : zl;
#pragma unroll
    for (int j = 0; j < 4; j++) {
      const int col = j * 16 + (lane & 15);       // 0..63 within zloc or u
      const float bias = bp[col];
#pragma unroll
      for (int r = 0; r < 4; r++) {
        const int row = rg2 * 16 + (lane >> 4) * 4 + r;
        outp[row * 64 + col] = acc2[j][r] + bias;
      }
    }
  }
  __syncthreads();

  // ---- phase 6: langevin + logq + winner scatter (wave w: rows w*8..w*8+7) -
  {
    const float* zl = (const float*)(smem + 65536);
    const float* ul = (const float*)(smem + 81920);
    const float coef = sqrtf(2.f * EPSI);
    const long strideN = (long)B * ZD;
    for (int q = 0; q < 8; q++) {
      const int lr = w * 8 + q;
      const int gr = m0 + lr;
      const int i = idx[gr];
      const float zloc = zl[lr * 64 + lane];
      const float uu = ul[lr * 64 + lane];
      const float a = EPSI * expf(-2.f * uu);
      float z = cache[(long)i * ZD + lane];
      const float* np = noise + (long)gr * ZD + lane;
#pragma unroll
      for (int s = 0; s < NSTEPS; s++) {
        z = z + a * (zloc - z) + coef * np[(long)s * strideN];
      }
      out_z[(long)gr * ZD + lane] = z;
      if (winner[i] == gr + 1) {
        out_cache[(long)i * ZD + lane] = z;
      }
      const float d = (z - zloc) * expf(-uu);
      float t = -0.5f * d * d - uu - 0.91893853320467274178f;
#pragma unroll
      for (int off = 1; off < 64; off <<= 1) t += __shfl_xor(t, off);
      if (lane == 0) out_logq[gr] = t;
    }
  }
}

extern "C" void kernel_launch(void* const* d_in, const int* in_sizes, int n_in,
                              void* d_out, int out_size, void* d_ws, size_t ws_size,
                              hipStream_t stream) {
  const float* x     = (const float*)d_in[0];
  const int*   idx   = (const int*)d_in[1];
  const float* W1    = (const float*)d_in[3];
  const float* b1    = (const float*)d_in[4];
  const float* W21   = (const float*)d_in[5];
  const float* b21   = (const float*)d_in[6];
  const float* W22   = (const float*)d_in[7];
  const float* b22   = (const float*)d_in[8];
  const float* cache = (const float*)d_in[9];
  const float* noise = (const float*)d_in[10];

  const int B  = in_sizes[1];            // 16384
  const int DS = in_sizes[9] / ZD;       // 1000000

  float* out_logq  = (float*)d_out;
  float* out_z     = out_logq + B;
  float* out_cache = out_z + (long)B * ZD;

  // workspace: W1p 800KB + Woutp 128KB + win 4MB  (~5MB)
  short* w1p   = (short*)d_ws;                        // 51200*8 bf16
  short* woutp = w1p + (long)NW1SLOTS * 8;            // 8192*8 bf16
  int*   win   = (int*)(woutp + (long)NWOSLOTS * 8);  // DS ints

  const int n4i = (DS + 3) / 4;
  zero_win_kernel<<<(n4i + 255) / 256, 256, 0, stream>>>((i32x4*)win, n4i);

  const int prep_slots = NW1SLOTS + NWOSLOTS;         // 59392
  prep_kernel<<<(prep_slots + 255) / 256, 256, 0, stream>>>(W1, W21, W22, w1p, woutp);
  winner_kernel<<<(B + 255) / 256, 256, 0, stream>>>(idx, win, B);

  const long n4 = (long)DS * (ZD / 4);                // 16,000,000 float4
  copy_kernel<<<(unsigned)(n4 / 1024), 256, 0, stream>>>(
      (const f32x4*)cache, (f32x4*)out_cache);

  mega_kernel<<<B / 64, 512, 0, stream>>>(
      x, w1p, woutp, b1, b21, b22, cache, idx, noise, win,
      out_logq, out_z, out_cache, B);
}